// Round 7
// baseline (97.861 us; speedup 1.0000x reference)
//
#include <hip/hip_runtime.h>

#define Bb 4
#define AT 384
#define NBR 24
#define FEAT 128
#define ROWQ (FEAT / 4)            // 32 float4 per feature row
#define TILEQ (NBR * ROWQ)         // 768 float4 per (b,a,j) tile / per (b,a) panel
#define NTILES (Bb * AT * NBR)     // 36864

typedef float vfloat4 __attribute__((ext_vector_type(4)));

// Persistent, barrier-free, LDS-free. Each WAVE grid-strides over (b,a,j)
// tiles. Mask per tile entirely in registers:
//   key = idx | cell0<<9 | cell1<<11 | cell2<<13  (idx<384=9 bits, cells in 0..2)
//   match[i] = exists k<24: key_i == key_k(row jatom)
// computed with a 24-step readlane-broadcast compare + ballot. Then 12
// independent dwordx4 stores (12 KB), with a pure-fill path when mask==0.
__global__ __launch_bounds__(256) void edgejk_kernel(
    const vfloat4* __restrict__ edge,   // (B, AT, NBR, FEAT) as float4
    const int*     __restrict__ nbr,    // (B, AT, NBR)
    const float*   __restrict__ cell,   // (B, AT, NBR, 3)
    vfloat4*       __restrict__ out)    // (B, AT, NBR_j, NBR_i, FEAT)
{
    const int lane = threadIdx.x & 63;
    const int wid  = (blockIdx.x << 2) | (threadIdx.x >> 6);  // global wave id
    const int nw   = gridDim.x << 2;                          // total waves
    const int li   = (lane < NBR) ? lane : 0;                 // clamped i

    const vfloat4 zero = (vfloat4)(0.f);

    for (int tile = wid; tile < NTILES; tile += nw) {
        const int j  = tile % NBR;
        const int ba = tile / NBR;     // b*AT + a
        const int b  = ba / AT;

        // i-side key (lane = i), independent loads
        const int   base_i = ba * NBR + li;
        const int   idx_i  = nbr[base_i];
        const float a0 = cell[base_i * 3 + 0];
        const float a1 = cell[base_i * 3 + 1];
        const float a2 = cell[base_i * 3 + 2];
        const int key_i = idx_i | ((int)a0 << 9) | ((int)a1 << 11) | ((int)a2 << 13);

        // j-side keys: neighbors of atom jatom = nbr[b,a,j] (lane j's idx_i)
        const int   jatom  = __shfl(idx_i, j);
        const int   base_k = (b * AT + jatom) * NBR + li;
        const int   idx_k  = nbr[base_k];
        const float b0 = cell[base_k * 3 + 0];
        const float b1 = cell[base_k * 3 + 1];
        const float b2 = cell[base_k * 3 + 2];
        const int key_k = idx_k | ((int)b0 << 9) | ((int)b1 << 11) | ((int)b2 << 13);

        // all-pairs: does my key_i match any of the 24 broadcast key_k's?
        bool m = false;
        #pragma unroll
        for (int s = 0; s < NBR; ++s)
            m |= (key_i == __shfl(key_k, s));
        m = m && (lane < NBR) && (lane != j);
        const unsigned long long w = __ballot(m);   // bit i = mask[j][i]

        const vfloat4* __restrict__ erow = edge + (size_t)ba * TILEQ;
        vfloat4*       __restrict__ orow = out  + (size_t)tile * TILEQ;

        if (w == 0ull) {
            // pure fill: 12 independent dwordx4 stores, no dependencies
            #pragma unroll
            for (int it = 0; it < 12; ++it)
                orow[it * 64 + lane] = zero;
        } else {
            #pragma unroll
            for (int it = 0; it < 12; ++it) {
                const int q = it * 64 + lane;   // [0, 768)
                const int i = q >> 5;           // neighbor row (32 float4 each)
                vfloat4 v = zero;
                if ((w >> i) & 1ull) v = erow[q];
                orow[q] = v;
            }
        }
    }
}

extern "C" void kernel_launch(void* const* d_in, const int* in_sizes, int n_in,
                              void* d_out, int out_size, void* d_ws, size_t ws_size,
                              hipStream_t stream) {
    const vfloat4* edge = (const vfloat4*)d_in[0];
    const int*     nbr  = (const int*)d_in[1];
    const float*   cell = (const float*)d_in[2];
    vfloat4*       out  = (vfloat4*)d_out;

    // 2048 blocks x 256 thr = 8 blocks/CU, 32 waves/CU (full occupancy),
    // 8192 persistent waves, ~4.5 tiles each.
    edgejk_kernel<<<2048, 256, 0, stream>>>(edge, nbr, cell, out);
}